// Round 10
// baseline (438.554 us; speedup 1.0000x reference)
//
#include <hip/hip_runtime.h>
#include <hip/hip_bf16.h>

#define N_ATOMS 100000
#define N_PAIRS 2000000
#define N_EMB 30
#define N_DIST 100
#define N_HID 60

#define EBLOCKS 512                 // 2 blocks/CU, 2048 autonomous waves
#define NW (EBLOCKS * 4)
#define NCHUNK (N_PAIRS / 16)       // 125000 16-edge chunks

typedef short bf16x8 __attribute__((ext_vector_type(8)));
typedef float f32x4 __attribute__((ext_vector_type(4)));

__device__ __forceinline__ ushort f2bf(float f) {
    __hip_bfloat16 h = __float2bfloat16(f);
    return __builtin_bit_cast(ushort, h);
}
__device__ __forceinline__ float fast_tanh(float x) {
    float e = __expf(2.0f * x);
    return 1.0f - 2.0f / (e + 1.0f);
}

// ---------------- Kernel A: per-atom hidden + output init ----------------
__global__ __launch_bounds__(256) void atom_kernel(
    const float* __restrict__ af, const float* __restrict__ W_cf,
    const float* __restrict__ W_fc, const float* __restrict__ b_cf,
    const float* __restrict__ b_df, float* __restrict__ ah_out,
    float* __restrict__ out)
{
    __shared__ __align__(16) float ah_lds[4][N_HID];
    const int wave = threadIdx.x >> 6;
    const int lane = threadIdx.x & 63;
    const int n = blockIdx.x * 4 + wave;

    float ahv = 0.f;
    if (lane < N_HID) {
        ahv = b_cf[lane];
        #pragma unroll
        for (int k = 0; k < N_EMB; ++k)
            ahv = fmaf(af[(size_t)n * N_EMB + k], W_cf[k * N_HID + lane], ahv);
        ah_out[(size_t)n * N_HID + lane] = ahv;
        ah_lds[wave][lane] = ahv * b_df[lane];
    }
    __syncthreads();
    if (lane < N_EMB) {
        float s = 0.f;
        #pragma unroll
        for (int h = 0; h < N_HID; ++h)
            s = fmaf(ah_lds[wave][h], W_fc[h * N_EMB + lane], s);
        out[(size_t)n * N_EMB + lane] =
            af[(size_t)n * N_EMB + lane] - fast_tanh(s);
    }
}

// ---------------- Kernel B: wave-autonomous, 2-deep prefetch, zero barriers ----------------
// Per wave per chunk (16 edges):
//  pack pf(c) -> bf16 a-frags ; issue gather(c) ; issue pf <- chunk c+1
//  MFMA1: dist[16x100] @ wdf[100x60] (weights in VGPRs, single bf16)
//  T = (dh + b_df) * ah[mj] -> wave-private LDS transpose bounce (lgkm only)
//  MFMA2: T[16x60] @ wfc[60x30] -> tanh -> per-lane segment scan -> atomics
__global__ __launch_bounds__(256, 2) void edge_kernel(
    const float* __restrict__ dist,
    const int* __restrict__ mi, const int* __restrict__ mj,
    const float* __restrict__ W_df, const float* __restrict__ W_fc,
    const float* __restrict__ b_df, const float* __restrict__ ah,
    float* out)
{
    __shared__ ushort T_all[4][16 * 72];      // wave-private T, 2304 B each
    const int tid = threadIdx.x;
    const int wv = tid >> 6, lane = tid & 63;
    const int l4 = lane >> 4, ln = lane & 15;
    ushort* Tw = T_all[wv];

    // ---- one-time weight fragments (single bf16; hi/lo dropped per r8/r9 evidence) ----
    bf16x8 wdf[4][4];                         // [ks][hg]: k=ks*32+l4*8+i, h=hg*16+ln
    #pragma unroll
    for (int ks = 0; ks < 4; ++ks) {
        #pragma unroll
        for (int hg = 0; hg < 4; ++hg) {
            #pragma unroll
            for (int i = 0; i < 8; ++i) {
                int k = ks * 32 + l4 * 8 + i, h = hg * 16 + ln;
                float f = (k < N_DIST && h < N_HID) ? W_df[k * N_HID + h] : 0.f;
                wdf[ks][hg][i] = (short)f2bf(f);
            }
        }
    }
    bf16x8 wfc[2][2];                         // [nf][ks]: k=ks*32+l4*8+i, col=nf*16+ln
    #pragma unroll
    for (int nf = 0; nf < 2; ++nf) {
        #pragma unroll
        for (int ks = 0; ks < 2; ++ks) {
            #pragma unroll
            for (int i = 0; i < 8; ++i) {
                int k = ks * 32 + l4 * 8 + i, n = nf * 16 + ln;
                float f = (k < N_HID && n < N_EMB) ? W_fc[k * N_EMB + n] : 0.f;
                wfc[nf][ks][i] = (short)f2bf(f);
            }
        }
    }
    float bdf[4];
    #pragma unroll
    for (int hg = 0; hg < 4; ++hg) {
        int h = hg * 16 + ln;
        bdf[hg] = (h < N_HID) ? b_df[h] : 0.f;
    }

    const int gw = blockIdx.x * 4 + wv;
    const int c0 = (int)(((long long)gw * NCHUNK) / NW);
    const int c1 = (int)(((long long)(gw + 1) * NCHUNK) / NW);

    // ---- prefetch bank (one chunk in flight) ----
    f32x4 pf[7];
    int pmi = 0, pmj = 0;
    auto issue = [&](int c) {
        const float* rowp = dist + (size_t)(c * 16 + ln) * N_DIST;
        pf[0] = __builtin_nontemporal_load((const f32x4*)(rowp + l4 * 8));
        pf[1] = __builtin_nontemporal_load((const f32x4*)(rowp + l4 * 8 + 4));
        pf[2] = __builtin_nontemporal_load((const f32x4*)(rowp + 32 + l4 * 8));
        pf[3] = __builtin_nontemporal_load((const f32x4*)(rowp + 32 + l4 * 8 + 4));
        pf[4] = __builtin_nontemporal_load((const f32x4*)(rowp + 64 + l4 * 8));
        pf[5] = __builtin_nontemporal_load((const f32x4*)(rowp + 64 + l4 * 8 + 4));
        if (l4 == 0) pf[6] = __builtin_nontemporal_load((const f32x4*)(rowp + 96));
        pmi = mi[c * 16 + ln];
        pmj = mj[c * 16 + ln];
    };

    issue(c0);   // prologue

    for (int c = c0; c < c1; ++c) {
        const int miv = pmi, mjv = pmj;       // copied before pf bank is reused

        // ---- pack pf -> bf16 a-frags (waits on pf; issued a full chunk ago) ----
        bf16x8 a[4];
        #pragma unroll
        for (int i = 0; i < 4; ++i) {
            a[0][i] = (short)f2bf(pf[0][i]); a[0][4 + i] = (short)f2bf(pf[1][i]);
            a[1][i] = (short)f2bf(pf[2][i]); a[1][4 + i] = (short)f2bf(pf[3][i]);
            a[2][i] = (short)f2bf(pf[4][i]); a[2][4 + i] = (short)f2bf(pf[5][i]);
            a[3][i] = (l4 == 0) ? (short)f2bf(pf[6][i]) : (short)0;
            a[3][4 + i] = (short)0;
        }

        // ---- gather ah FIRST (its waitcnt must not drain the dist prefetch below) ----
        int jr[4];
        #pragma unroll
        for (int r = 0; r < 4; ++r) jr[r] = __shfl(mjv, l4 * 4 + r);
        float ahg[4][4];
        #pragma unroll
        for (int hg = 0; hg < 4; ++hg) {
            int h = hg * 16 + ln;
            #pragma unroll
            for (int r = 0; r < 4; ++r)
                ahg[hg][r] = (h < N_HID) ? ah[(size_t)jr[r] * N_HID + h] : 0.f;
        }

        // ---- issue next chunk's loads (in flight across the whole chunk) ----
        if (c + 1 < c1) issue(c + 1);

        // ---- MFMA1: 16 edges x 60 hid ----
        f32x4 acc1[4] = {{0,0,0,0},{0,0,0,0},{0,0,0,0},{0,0,0,0}};
        #pragma unroll
        for (int ks = 0; ks < 4; ++ks) {
            #pragma unroll
            for (int hg = 0; hg < 4; ++hg)
                acc1[hg] = __builtin_amdgcn_mfma_f32_16x16x32_bf16(a[ks], wdf[ks][hg], acc1[hg], 0, 0, 0);
        }

        // ---- T = (dh + b_df) * ah -> bf16 -> wave-private LDS transpose ----
        #pragma unroll
        for (int hg = 0; hg < 4; ++hg) {
            #pragma unroll
            for (int r = 0; r < 4; ++r) {
                float tv = (acc1[hg][r] + bdf[hg]) * ahg[hg][r];
                Tw[(l4 * 4 + r) * 72 + hg * 16 + ln] = f2bf(tv);
            }
        }
        // same-wave RAW: compiler inserts lgkmcnt before these reads
        bf16x8 t0 = *(const bf16x8*)&Tw[ln * 72 + l4 * 8];
        bf16x8 t1 = *(const bf16x8*)&Tw[ln * 72 + 32 + l4 * 8];

        // ---- MFMA2: 16 edges x 30 f ----
        f32x4 acc2[2] = {{0,0,0,0},{0,0,0,0}};
        #pragma unroll
        for (int nf = 0; nf < 2; ++nf) {
            acc2[nf] = __builtin_amdgcn_mfma_f32_16x16x32_bf16(t0, wfc[nf][0], acc2[nf], 0, 0, 0);
            acc2[nf] = __builtin_amdgcn_mfma_f32_16x16x32_bf16(t1, wfc[nf][1], acc2[nf], 0, 0, 0);
        }

        // ---- tanh + per-lane segment scan over this lane's 4 edges ----
        float s0v[4], s1v[4];
        #pragma unroll
        for (int r = 0; r < 4; ++r) {
            s0v[r] = fast_tanh(acc2[0][r]);
            s1v[r] = fast_tanh(acc2[1][r]);
        }
        int m_r[4];
        #pragma unroll
        for (int r = 0; r < 4; ++r) m_r[r] = __shfl(miv, l4 * 4 + r);

        int cura = m_r[0];
        float f0 = s0v[0], f1 = s1v[0];
        #pragma unroll
        for (int r = 1; r < 4; ++r) {
            if (m_r[r] != cura) {
                atomicAdd(&out[(size_t)cura * N_EMB + ln], f0);
                if (ln < N_EMB - 16) atomicAdd(&out[(size_t)cura * N_EMB + 16 + ln], f1);
                cura = m_r[r]; f0 = s0v[r]; f1 = s1v[r];
            } else {
                f0 += s0v[r]; f1 += s1v[r];
            }
        }
        atomicAdd(&out[(size_t)cura * N_EMB + ln], f0);
        if (ln < N_EMB - 16) atomicAdd(&out[(size_t)cura * N_EMB + 16 + ln], f1);
    }
}

extern "C" void kernel_launch(void* const* d_in, const int* in_sizes, int n_in,
                              void* d_out, int out_size, void* d_ws, size_t ws_size,
                              hipStream_t stream) {
    const float* af   = (const float*)d_in[0];
    const float* dist = (const float*)d_in[1];
    const int*   mi   = (const int*)d_in[2];
    const int*   mj   = (const int*)d_in[3];
    const float* W_cf = (const float*)d_in[4];
    const float* W_df = (const float*)d_in[5];
    const float* W_fc = (const float*)d_in[6];
    const float* b_cf = (const float*)d_in[7];
    const float* b_df = (const float*)d_in[8];
    float* out = (float*)d_out;
    float* ah  = (float*)d_ws;   // N_ATOMS * N_HID floats = 24 MB

    atom_kernel<<<N_ATOMS / 4, 256, 0, stream>>>(af, W_cf, W_fc, b_cf, b_df, ah, out);
    edge_kernel<<<EBLOCKS, 256, 0, stream>>>(dist, mi, mj, W_df, W_fc, b_df, ah, out);
}